// Round 6
// baseline (126.494 us; speedup 1.0000x reference)
//
#include <hip/hip_runtime.h>
#include <hip/hip_cooperative_groups.h>
#include <math.h>

namespace cg = cooperative_groups;

// Cox partial-likelihood loss, N = 16384 — single cooperative kernel.
//   T = |y|, E = (y > 0), theta = y_hat, e = exp(theta)
//   risk[i] = sum over 64 sorted chunks c of suffix_c[ lower_bound_c(T_i) ]
//   loss = -mean((theta - log(risk)) * E)
//
// Grid: 256 blocks x 1024 threads, 132 KB LDS -> exactly 1 block/CU on all
// 256 CUs (cooperative co-residency).
// Phase A (blocks 0..15): each sorts 4 chunks of 256 by T (bitonic, e rides
//   along) + inclusive suffix sum of e -> sortedT/sortedS in ws; block 0
//   zeroes out[0]. __threadfence() then grid.sync().
// Phase B (all blocks): stage both tables into LDS (128 KB), block owns 64
//   i's; thread group g of 16 searches 4 chunks for its i; LDS reduce across
//   groups; wave 0 computes terms, reduces, one atomicAdd(out) per block.

#define CSZ     256
#define NCH     64
#define N_      16384
#define IPB     64
#define THREADS 1024
#define BLOCKS  (N_ / IPB)   // 256

__global__ void __launch_bounds__(THREADS, 4) cox_fused(
        const float* __restrict__ y_hat, const float* __restrict__ y,
        float* __restrict__ sortedT, float* __restrict__ sortedS,
        float* __restrict__ out, int n) {
    __shared__ float sT[N_];              // 64 KB
    __shared__ float sS[N_];              // 64 KB
    __shared__ float part[16][IPB];       // 4 KB

    const int tid = threadIdx.x;
    cg::grid_group grid = cg::this_grid();

    // ---------------- Phase A: sort + suffix scan (blocks 0..15) ------------
    if (blockIdx.x < 16) {
        const int sub  = tid >> 8;                 // 0..3: which chunk in block
        const int el   = tid & 255;                // element within chunk
        const int c    = (blockIdx.x << 2) + sub;  // global chunk id 0..63
        const int base = sub << 8;                 // LDS sub-region

        sT[base + el] = fabsf(y[(c << 8) + el]);
        sS[base + el] = expf(y_hat[(c << 8) + el]);
        __syncthreads();

        // bitonic sort ascending by T, e rides along (36 compare stages)
        for (int k = 2; k <= CSZ; k <<= 1) {
            for (int j = k >> 1; j > 0; j >>= 1) {
                int ixj = el ^ j;
                if (ixj > el) {
                    float t0 = sT[base + el], t1 = sT[base + ixj];
                    bool up = ((el & k) == 0);
                    if (up ? (t0 > t1) : (t0 < t1)) {
                        sT[base + el] = t1; sT[base + ixj] = t0;
                        float e0 = sS[base + el];
                        sS[base + el] = sS[base + ixj]; sS[base + ixj] = e0;
                    }
                }
                __syncthreads();
            }
        }

        // inclusive suffix sum of e (doubling, 8 steps)
        for (int d = 1; d < CSZ; d <<= 1) {
            float add = (el + d < CSZ) ? sS[base + el + d] : 0.0f;
            __syncthreads();
            sS[base + el] += add;
            __syncthreads();
        }

        sortedT[(c << 8) + el] = sT[base + el];
        sortedS[(c << 8) + el] = sS[base + el];
    }
    if (blockIdx.x == 0 && tid == 0) out[0] = 0.0f;

    __threadfence();          // device-scope release of phase-A writes
    grid.sync();              // grid-wide barrier + memory visibility

    // ---------------- Phase B: LDS search + fused loss reduce ---------------
    {
        const float4* gT = (const float4*)sortedT;
        const float4* gS = (const float4*)sortedS;
        float4* lT = (float4*)sT;
        float4* lS = (float4*)sS;
        #pragma unroll
        for (int k = tid; k < N_ / 4; k += THREADS) {
            lT[k] = gT[k];
            lS[k] = gS[k];
        }
    }
    __syncthreads();

    const int il = tid & 63;              // which of this block's 64 i's
    const int g  = tid >> 6;              // chunk group 0..15
    const int i  = blockIdx.x * IPB + il;
    const float Ti = fabsf(y[i]);

    float r = 0.0f;
    #pragma unroll
    for (int cc = 0; cc < 4; ++cc) {
        const int c = (g << 2) + cc;
        const float* Tc = &sT[c << 8];
        // branchless lower_bound: first pos with Tc[pos] >= Ti, pos in [0,256]
        int pos = 0;
        #pragma unroll
        for (int half = CSZ >> 1; half >= 1; half >>= 1)
            if (Tc[pos + half - 1] < Ti) pos += half;
        if (Tc[pos] < Ti) pos += 1;
        r += (pos < CSZ) ? sS[(c << 8) + pos] : 0.0f;
    }
    part[g][il] = r;
    __syncthreads();

    if (tid < 64) {
        float risk = 0.0f;
        #pragma unroll
        for (int g2 = 0; g2 < 16; ++g2) risk += part[g2][tid];
        float E = (y[i] > 0.0f) ? 1.0f : 0.0f;
        float term = (y_hat[i] - logf(risk)) * E;
        #pragma unroll
        for (int off = 32; off >= 1; off >>= 1)
            term += __shfl_down(term, off, 64);
        if (tid == 0) atomicAdd(out, -term / (float)n);
    }
}

extern "C" void kernel_launch(void* const* d_in, const int* in_sizes, int n_in,
                              void* d_out, int out_size, void* d_ws, size_t ws_size,
                              hipStream_t stream) {
    const float* y_hat = (const float*)d_in[0];
    const float* y     = (const float*)d_in[1];
    float* out = (float*)d_out;
    int n = in_sizes[0];   // 16384

    float* sortedT = (float*)d_ws;
    float* sortedS = sortedT + n;

    void* args[] = { (void*)&y_hat, (void*)&y, (void*)&sortedT,
                     (void*)&sortedS, (void*)&out, (void*)&n };
    hipLaunchCooperativeKernel((const void*)cox_fused,
                               dim3(BLOCKS), dim3(THREADS),
                               args, 0, stream);
}

// Round 7
// 18.686 us; speedup vs baseline: 6.7696x; 6.7696x over previous
//
#include <hip/hip_runtime.h>
#include <math.h>

// Cox partial-likelihood loss, N = 16384 — sorted-chunk suffix-sum scheme.
//   T = |y|, E = (y > 0), theta = y_hat, e = exp(theta)
//   risk[i] = sum over 64 sorted chunks c of suffix_c[ lower_bound_c(T_i) ]
//   loss = -mean((theta - log(risk)) * E)
//
// K0: 64 blocks x 256 thr — per-chunk bitonic sort by T, register-resident:
//     33/36 stages via __shfl_xor (partner tid^j, j<64, intra-wave), only
//     j in {64,128} through LDS (3 stages, 6 barriers). Suffix sum of e via
//     in-wave __shfl_down doubling + 4-word cross-wave combine (2 barriers).
// K1: 256 blocks x 1024 thr — each block owns 64 i's; stages BOTH tables in
//     LDS (128 KB, 1 block/CU, all 256 CUs, 16 waves for TLP); thread group
//     g of 16 searches 4 chunks for its i; LDS reduce across groups; wave 0
//     computes terms, reduces, one atomicAdd(out) per block.

#define CSZ  256
#define NCH  64
#define N_   16384
#define IPB  64

// ---------------- K0: shfl-bitonic sort + suffix scan ----------------
__global__ void __launch_bounds__(CSZ) cox_sort(
        const float* __restrict__ y_hat, const float* __restrict__ y,
        float* __restrict__ sortedT, float* __restrict__ sortedS,
        float* __restrict__ out) {
    __shared__ float xT[CSZ];
    __shared__ float xE[CSZ];
    __shared__ float wtot[4];

    const int tid  = threadIdx.x;
    const int base = blockIdx.x * CSZ;

    float t = fabsf(y[base + tid]);
    float e = expf(y_hat[base + tid]);
    if (base + tid == 0) out[0] = 0.0f;

    // bitonic sort ascending by T; e rides along. Thread tid holds pos tid.
    #pragma unroll
    for (int k = 2; k <= CSZ; k <<= 1) {
        #pragma unroll
        for (int j = k >> 1; j > 0; j >>= 1) {
            const bool up      = ((tid & k) == 0);
            const bool lower   = ((tid & j) == 0);
            const bool takeMin = (lower == up);
            float tp, ep;
            if (j >= 64) {                       // cross-wave: via LDS
                __syncthreads();                 // protect prior stage reads
                xT[tid] = t; xE[tid] = e;
                __syncthreads();
                tp = xT[tid ^ j]; ep = xE[tid ^ j];
            } else {                             // intra-wave: register shfl
                tp = __shfl_xor(t, j, 64);
                ep = __shfl_xor(e, j, 64);
            }
            const bool ownWins = takeMin ? (t <= tp) : (t >= tp);
            t = takeMin ? fminf(t, tp) : fmaxf(t, tp);
            e = ownWins ? e : ep;
        }
    }

    // inclusive suffix sum of e: in-wave shfl doubling, then cross-wave
    const int lane = tid & 63, wv = tid >> 6;
    float s = e;
    #pragma unroll
    for (int d = 1; d < 64; d <<= 1) {
        float v = __shfl_down(s, d, 64);
        if (lane + d < 64) s += v;
    }
    if (lane == 0) wtot[wv] = s;                 // wave suffix-total
    __syncthreads();
    #pragma unroll
    for (int w = 0; w < 4; ++w)
        if (w > wv) s += wtot[w];

    sortedT[base + tid] = t;
    sortedS[base + tid] = s;
}

// ---------------- K1: all-CU LDS search + fused loss reduce ----------------
__global__ void __launch_bounds__(1024, 4) cox_search(
        const float* __restrict__ y_hat, const float* __restrict__ y,
        const float* __restrict__ sortedT, const float* __restrict__ sortedS,
        float* __restrict__ out, int n) {
    __shared__ float sT[N_];              // 64 KB: all sorted T
    __shared__ float sS[N_];              // 64 KB: all suffix sums
    __shared__ float part[16][IPB];       // 4 KB: per-group partial risks

    const int tid = threadIdx.x;
    const int il  = tid & 63;             // which of this block's 64 i's
    const int g   = tid >> 6;             // chunk group 0..15
    const int i   = blockIdx.x * IPB + il;

    // hoist global loads above staging to hide latency
    const float Ti = fabsf(y[i]);
    const float yh = y_hat[i];
    const float E  = (y[i] > 0.0f) ? 1.0f : 0.0f;

    // stage both tables (float4, coalesced, L2-resident source)
    {
        const float4* gT = (const float4*)sortedT;
        const float4* gS = (const float4*)sortedS;
        float4* lT = (float4*)sT;
        float4* lS = (float4*)sS;
        #pragma unroll
        for (int k = tid; k < N_ / 4; k += 1024) {
            lT[k] = gT[k];
            lS[k] = gS[k];
        }
    }
    __syncthreads();

    float r = 0.0f;
    #pragma unroll
    for (int cc = 0; cc < 4; ++cc) {
        const int c = (g << 2) + cc;
        const float* Tc = &sT[c << 8];
        // branchless lower_bound: first pos with Tc[pos] >= Ti, pos in [0,256]
        int pos = 0;
        #pragma unroll
        for (int half = CSZ >> 1; half >= 1; half >>= 1)
            if (Tc[pos + half - 1] < Ti) pos += half;
        if (Tc[pos] < Ti) pos += 1;
        r += (pos < CSZ) ? sS[(c << 8) + pos] : 0.0f;
    }
    part[g][il] = r;
    __syncthreads();

    if (tid < 64) {
        float risk = 0.0f;
        #pragma unroll
        for (int g2 = 0; g2 < 16; ++g2) risk += part[g2][tid];
        float term = (yh - logf(risk)) * E;
        #pragma unroll
        for (int off = 32; off >= 1; off >>= 1)
            term += __shfl_down(term, off, 64);
        if (tid == 0) atomicAdd(out, -term / (float)n);
    }
}

extern "C" void kernel_launch(void* const* d_in, const int* in_sizes, int n_in,
                              void* d_out, int out_size, void* d_ws, size_t ws_size,
                              hipStream_t stream) {
    const float* y_hat = (const float*)d_in[0];
    const float* y     = (const float*)d_in[1];
    float* out = (float*)d_out;
    const int n = in_sizes[0];   // 16384

    float* sortedT = (float*)d_ws;
    float* sortedS = sortedT + n;

    cox_sort<<<n / CSZ, CSZ, 0, stream>>>(y_hat, y, sortedT, sortedS, out);
    cox_search<<<n / IPB, 1024, 0, stream>>>(y_hat, y, sortedT, sortedS, out, n);
}